// Round 5
// baseline (634.373 us; speedup 1.0000x reference)
//
#include <hip/hip_runtime.h>
#include <hip/hip_bf16.h>

#define NN 50000
#define NE 800000
#define DD 128
#define KSEL 25000
#define NBK 391                 // buckets of 128 nodes (graph build)
#define NBLKA 98                // (NE+8191)/8192
#define NCH 13                  // source chunks of 4096 rows (2MB fp32 / 1MB bf16)
#define PBLK 768                // persistent agg grid: 3 blocks/CU, all resident
#define PTH 512
#define NPB 66                  // nodes per persistent block (768*66 >= 50000)

typedef unsigned int uint32;
typedef unsigned short ushort16;

__device__ __forceinline__ float sigmoidf(float x){ return 1.f/(1.f+__expf(-x)); }

__device__ __forceinline__ unsigned short f2b(float f){
  union{float f; unsigned u;} v; v.f=f;
  unsigned r=(v.u + 0x7fffu + ((v.u>>16)&1u))>>16;
  return (unsigned short)r;
}

// ================= graph build: bucketed counting sort =================
__global__ __launch_bounds__(1024) void k_bcount(const int* __restrict__ dst,
    int* __restrict__ btot, int* __restrict__ blkcnt){
  __shared__ int h[NBK];
  int tid=threadIdx.x;
  for(int i=tid;i<NBK;i+=1024) h[i]=0;
  __syncthreads();
  int e0=blockIdx.x*8192;
  #pragma unroll
  for(int t=0;t<8;t++){
    int e=e0+t*1024+tid;
    if(e<NE) atomicAdd(&h[dst[e]>>7],1);
  }
  __syncthreads();
  for(int i=tid;i<NBK;i+=1024){
    int c=h[i];
    blkcnt[blockIdx.x*NBK+i]=c;
    if(c) atomicAdd(&btot[i],c);
  }
}

__global__ __launch_bounds__(512) void k_bscan(const int* __restrict__ btot,
    int* __restrict__ boff, const int* __restrict__ blkcnt, int* __restrict__ blkbase){
  __shared__ int sdata[512];
  int tid=threadIdx.x;
  int v=(tid<NBK)?btot[tid]:0;
  sdata[tid]=v; __syncthreads();
  for(int off=1;off<512;off<<=1){
    int y=(tid>=off)?sdata[tid-off]:0;
    __syncthreads();
    sdata[tid]+=y;
    __syncthreads();
  }
  int excl=sdata[tid]-v;
  if(tid<NBK) boff[tid]=excl;
  if(tid==NBK-1) boff[NBK]=excl+v;
  if(tid<NBK){
    int run=excl;
    for(int b=0;b<NBLKA;b++){
      int c=blkcnt[b*NBK+tid];
      blkbase[b*NBK+tid]=run;
      run+=c;
    }
  }
}

__global__ __launch_bounds__(1024) void k_bscatter(const int* __restrict__ src,
    const int* __restrict__ dst, const int* __restrict__ blkbase, uint2* __restrict__ pairs){
  __shared__ int cur[NBK];
  int tid=threadIdx.x;
  for(int i=tid;i<NBK;i+=1024) cur[i]=blkbase[blockIdx.x*NBK+i];
  __syncthreads();
  int e0=blockIdx.x*8192;
  #pragma unroll
  for(int t=0;t<8;t++){
    int e=e0+t*1024+tid;
    if(e<NE){
      int d=dst[e];
      int p=atomicAdd(&cur[d>>7],1);
      uint2 pr; pr.x=(unsigned)src[e]; pr.y=(unsigned)d;
      pairs[p]=pr;
    }
  }
}

// finalize: per-(node,chunk) sub-CSR + inv_sqrt(deg+1)
__global__ __launch_bounds__(256) void k_bfinal(const uint2* __restrict__ pairs,
    const int* __restrict__ boff, int* __restrict__ rowptr,
    float* __restrict__ inv_sq, int* __restrict__ csr_src){
  __shared__ int cnt[128*NCH];    // 6.5 KB
  __shared__ int cur[128*NCH];
  __shared__ int ssum[2];
  int b=blockIdx.x, tid=threadIdx.x;
  int lo=boff[b], hi=boff[b+1];
  for(int i=tid;i<128*NCH;i+=256) cnt[i]=0;
  __syncthreads();
  for(int e=lo+tid;e<hi;e+=256){
    uint2 pr=pairs[e];
    atomicAdd(&cnt[(pr.y&127)*NCH+(pr.x>>12)],1);
  }
  __syncthreads();
  int v=0,x=0;
  if(tid<128){
    #pragma unroll
    for(int c=0;c<NCH;c++) v+=cnt[tid*NCH+c];
    x=v;
    #pragma unroll
    for(int off=1;off<64;off<<=1){
      int y=__shfl_up(x,off,64);
      if((tid&63)>=off) x+=y;
    }
    if((tid&63)==63) ssum[tid>>6]=x;
  }
  __syncthreads();
  if(tid<128){
    int incl=x+((tid>=64)?ssum[0]:0);
    int node=b*128+tid;
    if(node<NN){
      int run=lo+incl-v;
      inv_sq[node]=1.f/sqrtf((float)(v+1));
      #pragma unroll
      for(int c=0;c<NCH;c++){
        rowptr[node*(NCH+1)+c]=run;
        cur[tid*NCH+c]=run;
        run+=cnt[tid*NCH+c];
      }
      rowptr[node*(NCH+1)+NCH]=run;
    }
  }
  __syncthreads();
  for(int e=lo+tid;e<hi;e+=256){
    uint2 pr=pairs[e];
    int p=atomicAdd(&cur[(pr.y&127)*NCH+(pr.x>>12)],1);
    csr_src[p]=(int)pr.x;
  }
}

// ---------------- 128x128 transpose (Wbil^T) ----------------
__global__ void k_transpose(const float* __restrict__ W, float* __restrict__ Wt){
  int idx=blockIdx.x*256+threadIdx.x;
  if(idx<DD*DD){
    int k=idx>>7, c=idx&127;
    Wt[idx]=W[c*DD+k];
  }
}

// ============ fp32 GEMM: 128x128 tile, 8x8 per thread ============
template<int IN_SIG,int ACT,int OUT_BF16,int FUSE_SCORE>
__global__ __launch_bounds__(256) void k_gemm128(const float* __restrict__ A,
    const float* __restrict__ W, const float* __restrict__ bias,
    float* __restrict__ outf, ushort16* __restrict__ outb,
    const float* __restrict__ aparam, const float* __restrict__ hp,
    const float* __restrict__ bbil, float* __restrict__ score){
  __shared__ float Al[128][132];
  int tid=threadIdx.x;
  int row0=blockIdx.x*128;
  {
    const float4* A4=(const float4*)(A+(size_t)row0*DD);
    #pragma unroll
    for(int i=0;i<16;i++){
      int idx=i*256+tid;
      int r=idx>>5, c=(idx&31)*4;
      float4 v=make_float4(0.f,0.f,0.f,0.f);
      if(row0+r<NN) v=A4[idx];
      if(IN_SIG){ v.x=sigmoidf(v.x); v.y=sigmoidf(v.y); v.z=sigmoidf(v.z); v.w=sigmoidf(v.w); }
      *(float4*)&Al[r][c]=v;
    }
  }
  __syncthreads();
  int tx=tid&15, ty=tid>>4;
  float acc[8][8];
  #pragma unroll
  for(int i=0;i<8;i++)
    #pragma unroll
    for(int c=0;c<8;c++) acc[i][c]=0.f;

  for(int k=0;k<DD;k+=4){
    float wv[4][8];
    #pragma unroll
    for(int r=0;r<4;r++){
      float4 lo=*(const float4*)&W[(size_t)(k+r)*DD+tx*8];
      float4 hi=*(const float4*)&W[(size_t)(k+r)*DD+tx*8+4];
      wv[r][0]=lo.x; wv[r][1]=lo.y; wv[r][2]=lo.z; wv[r][3]=lo.w;
      wv[r][4]=hi.x; wv[r][5]=hi.y; wv[r][6]=hi.z; wv[r][7]=hi.w;
    }
    #pragma unroll
    for(int i=0;i<8;i++){
      float4 a=*(const float4*)&Al[ty+16*i][k];
      #pragma unroll
      for(int c=0;c<8;c++)
        acc[i][c]+=a.x*wv[0][c]+a.y*wv[1][c]+a.z*wv[2][c]+a.w*wv[3][c];
    }
  }

  if(FUSE_SCORE){
    float bb=bbil[0];
    #pragma unroll
    for(int i=0;i<8;i++){
      int r=row0+ty+16*i;
      float p=0.f;
      if(r<NN){
        float4 h0=*(const float4*)&hp[(size_t)r*DD+tx*8];
        float4 h1=*(const float4*)&hp[(size_t)r*DD+tx*8+4];
        p=acc[i][0]*h0.x+acc[i][1]*h0.y+acc[i][2]*h0.z+acc[i][3]*h0.w
         +acc[i][4]*h1.x+acc[i][5]*h1.y+acc[i][6]*h1.z+acc[i][7]*h1.w;
      }
      p+=__shfl_xor(p,1,64); p+=__shfl_xor(p,2,64);
      p+=__shfl_xor(p,4,64); p+=__shfl_xor(p,8,64);
      if(tx==0 && r<NN) score[r]=sigmoidf(p+bb);
    }
    return;
  }
  float bl[8]={0,0,0,0,0,0,0,0};
  if(bias){
    float4 b0=*(const float4*)&bias[tx*8];
    float4 b1=*(const float4*)&bias[tx*8+4];
    bl[0]=b0.x; bl[1]=b0.y; bl[2]=b0.z; bl[3]=b0.w;
    bl[4]=b1.x; bl[5]=b1.y; bl[6]=b1.z; bl[7]=b1.w;
  }
  float ap=ACT?aparam[0]:0.f;
  #pragma unroll
  for(int i=0;i<8;i++){
    int r=row0+ty+16*i;
    if(r<NN){
      float o[8];
      #pragma unroll
      for(int c=0;c<8;c++){
        float t=acc[i][c]+bl[c];
        if(ACT) t=t>=0.f?t:ap*t;
        o[c]=t;
      }
      if(OUT_BF16){
        uint4 pk;
        pk.x=((uint32)f2b(o[1])<<16)|f2b(o[0]);
        pk.y=((uint32)f2b(o[3])<<16)|f2b(o[2]);
        pk.z=((uint32)f2b(o[5])<<16)|f2b(o[4]);
        pk.w=((uint32)f2b(o[7])<<16)|f2b(o[6]);
        *(uint4*)&outb[(size_t)r*DD+tx*8]=pk;
      } else {
        float4 q0; q0.x=o[0]; q0.y=o[1]; q0.z=o[2]; q0.w=o[3];
        float4 q1; q1.x=o[4]; q1.y=o[5]; q1.z=o[6]; q1.w=o[7];
        *(float4*)&outf[(size_t)r*DD+tx*8]=q0;
        *(float4*)&outf[(size_t)r*DD+tx*8+4]=q1;
      }
    }
  }
}

// ============ chunk-blocked persistent GCN aggregation ============
// MODE 0: fp32 xw -> out = agg+bias                     (embed)
// MODE 1: bf16 xw -> out = sel ? (agg+bias)*score : 0   (fine)
// MODE 2: bf16 xw (skip !sel[s]) -> out = agg+bias+addbuf
// All PBLK blocks co-resident; all sweep chunks in order -> gathers stay
// within a ~2MB window (L2-resident) instead of the full 25.6MB.
template<int MODE>
__global__ __launch_bounds__(PTH) void k_aggp(const void* __restrict__ xwv,
    const int* __restrict__ rowptr, const int* __restrict__ csr,
    const float* __restrict__ inv, const float* __restrict__ bias,
    float* __restrict__ outp, const float* __restrict__ score,
    const unsigned char* __restrict__ sel, const float* __restrict__ addbuf){
  __shared__ float acc[NPB][DD];      // 33 KB
  int tid=threadIdx.x, w=tid>>6, lane=tid&63;
  int g=lane>>5, li=lane&31;          // group handles cols [g*64, g*64+64)
  int base=blockIdx.x*NPB;
  for(int i=tid;i<NPB*DD/4;i+=PTH) ((float4*)&acc[0][0])[i]=make_float4(0.f,0.f,0.f,0.f);
  __syncthreads();
  const float* xwf=(const float*)xwv;
  const uint32* xwb=(const uint32*)xwv;
  for(int c=0;c<NCH;c++){
    for(int nl=w;nl<NPB;nl+=8){
      int n=base+nl; if(n>=NN) break;
      if(MODE==1 && !sel[n]) continue;
      int p0=rowptr[n*(NCH+1)+c], p1=rowptr[n*(NCH+1)+c+1];
      bool self=((n>>12)==c) && (MODE!=2 || sel[n]);
      if(p0>=p1 && !self) continue;
      float a0=0.f,a1=0.f;
      int j=p0;
      if(MODE==0){
        for(; j+1<p1; j+=2){
          int s0=csr[j], s1=csr[j+1];
          float w0=inv[s0], w1=inv[s1];
          float2 v0=*(const float2*)&xwf[(size_t)s0*DD+g*64+li*2];
          float2 v1=*(const float2*)&xwf[(size_t)s1*DD+g*64+li*2];
          a0+=v0.x*w0+v1.x*w1; a1+=v0.y*w0+v1.y*w1;
        }
        if(j<p1){
          int s=csr[j]; float wt=inv[s];
          float2 v=*(const float2*)&xwf[(size_t)s*DD+g*64+li*2];
          a0+=v.x*wt; a1+=v.y*wt;
        }
        if(self){
          float wt=inv[n];
          float2 v=*(const float2*)&xwf[(size_t)n*DD+g*64+li*2];
          a0+=v.x*wt; a1+=v.y*wt;
        }
      } else {
        for(; j+1<p1; j+=2){
          int s0=csr[j], s1=csr[j+1];
          bool t0=(MODE!=2)||sel[s0], t1=(MODE!=2)||sel[s1];
          uint32 u0=t0?xwb[(size_t)s0*64+g*32+li]:0u;
          uint32 u1=t1?xwb[(size_t)s1*64+g*32+li]:0u;
          float w0=t0?inv[s0]:0.f, w1=t1?inv[s1]:0.f;
          a0+=__uint_as_float(u0<<16)*w0+__uint_as_float(u1<<16)*w1;
          a1+=__uint_as_float(u0&0xffff0000u)*w0+__uint_as_float(u1&0xffff0000u)*w1;
        }
        if(j<p1){
          int s=csr[j];
          if(MODE!=2 || sel[s]){
            float wt=inv[s];
            uint32 u=xwb[(size_t)s*64+g*32+li];
            a0+=__uint_as_float(u<<16)*wt; a1+=__uint_as_float(u&0xffff0000u)*wt;
          }
        }
        if(self){
          float wt=inv[n];
          uint32 u=xwb[(size_t)n*64+g*32+li];
          a0+=__uint_as_float(u<<16)*wt; a1+=__uint_as_float(u&0xffff0000u)*wt;
        }
      }
      int col=g*64+li*2;
      float2 t=*(float2*)&acc[nl][col];
      t.x+=a0; t.y+=a1;
      *(float2*)&acc[nl][col]=t;
    }
  }
  // epilogue (each wave owns its nl set; no sync needed)
  for(int nl=w;nl<NPB;nl+=8){
    int n=base+nl; if(n>=NN) break;
    int col=lane*2;
    float2 t=*(const float2*)&acc[nl][col];
    float wn=inv[n];
    float2 bv=*(const float2*)&bias[col];
    float r0,r1;
    if(MODE==1){
      if(!sel[n]){ r0=0.f; r1=0.f; }
      else { float sc=score[n]; r0=(t.x*wn+bv.x)*sc; r1=(t.y*wn+bv.y)*sc; }
    } else if(MODE==2){
      float2 ad=*(const float2*)&addbuf[(size_t)n*DD+col];
      r0=t.x*wn+bv.x+ad.x; r1=t.y*wn+bv.y+ad.y;
    } else {
      r0=t.x*wn+bv.x; r1=t.y*wn+bv.y;
    }
    float2 o; o.x=r0; o.y=r1;
    *(float2*)&outp[(size_t)n*DD+col]=o;
  }
}

// ---------------- 3-pass radix select, LDS-privatized ----------
template<int NB,int PASS>
__global__ __launch_bounds__(256) void k_hist(const float* __restrict__ score,
    int* __restrict__ ghist, const int* __restrict__ ctrl){
  __shared__ int lh[NB];
  int tid=threadIdx.x;
  for(int i=tid;i<NB;i+=256) lh[i]=0;
  __syncthreads();
  int p0=0,p01=0;
  if(PASS==1) p0=ctrl[0];
  if(PASS==2) p01=ctrl[2];
  for(int i=blockIdx.x*256+tid; i<NN; i+=gridDim.x*256){
    unsigned b=__float_as_uint(score[i]);
    if(PASS==0) atomicAdd(&lh[b>>20],1);
    else if(PASS==1){ if((int)(b>>20)==p0) atomicAdd(&lh[(b>>8)&0xFFF],1); }
    else { if((int)(b>>8)==p01) atomicAdd(&lh[b&0xFF],1); }
  }
  __syncthreads();
  for(int i=tid;i<NB;i+=256){ int v=lh[i]; if(v) atomicAdd(&ghist[i],v); }
}

template<int NB,int PASS>
__global__ void k_findb(const int* __restrict__ hist, int* __restrict__ ctrl){
  const int NT=NB/4;
  __shared__ int gsum[NT];
  int t=threadIdx.x;
  int s=hist[t*4]+hist[t*4+1]+hist[t*4+2]+hist[t*4+3];
  int x=s; gsum[t]=x; __syncthreads();
  for(int off=1;off<NT;off<<=1){
    int y=(t+off<NT)?gsum[t+off]:0;
    __syncthreads();
    x+=y; gsum[t]=x; __syncthreads();
  }
  int base;
  if(PASS==0) base=0; else if(PASS==1) base=ctrl[1]; else base=ctrl[3];
  int above=base+((t<NT-1)?gsum[t+1]:0);
  int incl=base+gsum[t];
  if(above<KSEL && incl>=KSEL){
    int c=above, B=0;
    for(int b=3;b>=0;b--){
      int hb=hist[t*4+b];
      if(c+hb>=KSEL){ B=t*4+b; break; }
      c+=hb;
    }
    if(PASS==0){ ctrl[0]=B; ctrl[1]=c; }
    else if(PASS==1){ ctrl[2]=(ctrl[0]<<12)|B; ctrl[3]=c; }
    else { ctrl[4]=(int)((((unsigned)ctrl[2])<<8)|(unsigned)B); ctrl[5]=KSEL-c; }
  }
}

__global__ void k_sel(const float* __restrict__ score, int* __restrict__ ctrl,
                      int* __restrict__ tie_list, unsigned char* __restrict__ sel){
  int i=blockIdx.x*256+threadIdx.x;
  if(i>=NN) return;
  unsigned b=__float_as_uint(score[i]);
  unsigned thr=(unsigned)ctrl[4];
  if(b>thr){ sel[i]=1; }
  else if(b==thr){
    sel[i]=0;
    int p=atomicAdd(&ctrl[6],1);
    if(p<4096) tie_list[p]=i;
  } else sel[i]=0;
}

__global__ __launch_bounds__(256) void k_tie(const int* __restrict__ ctrl,
    const int* __restrict__ tie_list, unsigned char* __restrict__ sel){
  int m=ctrl[6]; if(m>4096) m=4096;
  int needed=ctrl[5];
  for(int t=threadIdx.x; t<m; t+=blockDim.x){
    int idx=tie_list[t];
    int rank=0;
    for(int j=0;j<m;j++) rank+=(tie_list[j]<idx)?1:0;
    if(rank<needed) sel[idx]=1;
  }
}

// ============================================================================
extern "C" void kernel_launch(void* const* d_in, const int* in_sizes, int n_in,
                              void* d_out, int out_size, void* d_ws, size_t ws_size,
                              hipStream_t stream){
  const float* feat   =(const float*)d_in[0];
  const int*   ei     =(const int*)  d_in[2];
  const int*   src    = ei;
  const int*   dst    = ei + NE;
  const float* Wd     =(const float*)d_in[3];
  const float* bd     =(const float*)d_in[4];
  const float* prelu_a=(const float*)d_in[5];
  const float* Wbil   =(const float*)d_in[6];
  const float* bbil   =(const float*)d_in[7];
  const float* Wg1    =(const float*)d_in[8];
  const float* bg1    =(const float*)d_in[9];
  const float* Wg2    =(const float*)d_in[10];
  const float* bg2    =(const float*)d_in[11];
  const float* Wg3    =(const float*)d_in[12];
  const float* bg3    =(const float*)d_in[13];
  float* out=(float*)d_out;

  char* p=(char*)d_ws;
  auto alloc=[&](size_t bytes)->void*{ void* r=(void*)p; p+=((bytes+255)/256)*256; return r; };
  float* h_pos   =(float*)alloc((size_t)NN*DD*4);
  float* embed   =(float*)alloc((size_t)NN*DD*4);
  float* xw      =(float*)alloc((size_t)NN*DD*4);   // fp32 xw1 / bf16 xw2,xw3 / pairs (early)
  float* score   =(float*)alloc((size_t)NN*4);
  float* inv_sq  =(float*)alloc((size_t)NN*4);
  float* WbT     =(float*)alloc((size_t)DD*DD*4);
  int*   rowptr  =(int*)  alloc((size_t)NN*(NCH+1)*4);
  int*   csr_src =(int*)  alloc((size_t)NE*4);
  int*   ctrl    =(int*)  alloc(64);
  int*   hist0   =(int*)  alloc(4096*4);
  int*   hist1   =(int*)  alloc(4096*4);
  int*   hist2   =(int*)  alloc(256*4);
  int*   tie_list=(int*)  alloc(4096*4);
  unsigned char* sel=(unsigned char*)alloc(NN);
  int*   btot    =(int*)  alloc((size_t)NBK*4);
  int*   boff    =(int*)  alloc((size_t)(NBK+1)*4);
  int*   blkcnt  =(int*)  alloc((size_t)NBLKA*NBK*4);
  int*   blkbase =(int*)  alloc((size_t)NBLKA*NBK*4);
  uint2* pairs   =(uint2*)xw;                       // aliased: lifetime before xw1
  ushort16* xwb  =(ushort16*)xw;
  float* fine = out;

  const int NB=(NN+255)/256;
  const int GB=(NN+127)/128;

  hipMemsetAsync(ctrl, 0, (size_t)((char*)tie_list-(char*)ctrl), stream);
  hipMemsetAsync(btot, 0, (size_t)NBK*4, stream);

  // graph structure: bucketed counting sort -> chunked sub-CSR + inv_sqrt
  k_bcount  <<<NBLKA,1024,0,stream>>>(dst, btot, blkcnt);
  k_bscan   <<<1,512,0,stream>>>(btot, boff, blkcnt, blkbase);
  k_bscatter<<<NBLKA,1024,0,stream>>>(src, dst, blkbase, pairs);
  k_bfinal  <<<NBK,256,0,stream>>>(pairs, boff, rowptr, inv_sq, csr_src);
  k_transpose<<<64,256,0,stream>>>(Wbil, WbT);

  // h_pos = prelu(feat @ Wd + bd)
  k_gemm128<0,1,0,0><<<GB,256,0,stream>>>(feat, Wd, bd, h_pos, nullptr, prelu_a, nullptr, nullptr, nullptr);
  // embed = gcn1(h_pos)
  k_gemm128<0,0,0,0><<<GB,256,0,stream>>>(h_pos, Wg1, nullptr, xw, nullptr, nullptr, nullptr, nullptr, nullptr);
  k_aggp<0><<<PBLK,PTH,0,stream>>>(xw, rowptr, csr_src, inv_sq, bg1, embed, nullptr, nullptr, nullptr);
  // score = sigmoid(rowdot(h_pos, sigmoid(embed)@Wbil^T) + bbil)   [fused]
  k_gemm128<1,0,0,1><<<GB,256,0,stream>>>(embed, WbT, nullptr, nullptr, nullptr, nullptr, h_pos, bbil, score);
  // top-k: 3-pass LDS-privatized radix select
  k_hist<4096,0><<<64,256,0,stream>>>(score, hist0, ctrl);
  k_findb<4096,0><<<1,1024,0,stream>>>(hist0, ctrl);
  k_hist<4096,1><<<64,256,0,stream>>>(score, hist1, ctrl);
  k_findb<4096,1><<<1,1024,0,stream>>>(hist1, ctrl);
  k_hist<256,2><<<64,256,0,stream>>>(score, hist2, ctrl);
  k_findb<256,2><<<1,64,0,stream>>>(hist2, ctrl);
  k_sel<<<NB,256,0,stream>>>(score, ctrl, tie_list, sel);
  k_tie<<<1,256,0,stream>>>(ctrl, tie_list, sel);
  // fine = sel ? gcn2(embed)*score : 0   (bf16 xw2)
  k_gemm128<0,0,1,0><<<GB,256,0,stream>>>(embed, Wg2, nullptr, nullptr, xwb, nullptr, nullptr, nullptr, nullptr);
  k_aggp<1><<<PBLK,PTH,0,stream>>>(xwb, rowptr, csr_src, inv_sq, bg2, fine, score, sel, nullptr);
  // out = gcn3(fine) + embed             (bf16 xw3, skip exact-zero rows)
  k_gemm128<0,0,1,0><<<GB,256,0,stream>>>(fine, Wg3, nullptr, nullptr, xwb, nullptr, nullptr, nullptr, nullptr);
  k_aggp<2><<<PBLK,PTH,0,stream>>>(xwb, rowptr, csr_src, inv_sq, bg3, out, nullptr, sel, embed);
}

// Round 6
// 394.528 us; speedup vs baseline: 1.6079x; 1.6079x over previous
//
#include <hip/hip_runtime.h>
#include <hip/hip_bf16.h>

#define NN 50000
#define NE 800000
#define DD 128
#define KSEL 25000
#define NBK 391                 // buckets of 128 nodes (graph build)
#define NBLKA 98                // (NE+8191)/8192

typedef unsigned int uint32;
typedef unsigned short ushort16;

__device__ __forceinline__ float sigmoidf(float x){ return 1.f/(1.f+__expf(-x)); }

__device__ __forceinline__ unsigned short f2b(float f){
  union{float f; unsigned u;} v; v.f=f;
  unsigned r=(v.u + 0x7fffu + ((v.u>>16)&1u))>>16;
  return (unsigned short)r;
}

__device__ __forceinline__ void addbf2(float&lo,float&hi,uint32 u,float w){
  lo+=__uint_as_float(u<<16)*w;
  hi+=__uint_as_float(u&0xffff0000u)*w;
}

// ================= graph build: bucketed counting sort =================
__global__ __launch_bounds__(1024) void k_bcount(const int* __restrict__ dst,
    int* __restrict__ btot, int* __restrict__ blkcnt){
  __shared__ int h[NBK];
  int tid=threadIdx.x;
  for(int i=tid;i<NBK;i+=1024) h[i]=0;
  __syncthreads();
  int e0=blockIdx.x*8192;
  #pragma unroll
  for(int t=0;t<8;t++){
    int e=e0+t*1024+tid;
    if(e<NE) atomicAdd(&h[dst[e]>>7],1);
  }
  __syncthreads();
  for(int i=tid;i<NBK;i+=1024){
    int c=h[i];
    blkcnt[blockIdx.x*NBK+i]=c;
    if(c) atomicAdd(&btot[i],c);
  }
}

__global__ __launch_bounds__(512) void k_bscan(const int* __restrict__ btot,
    int* __restrict__ boff, const int* __restrict__ blkcnt, int* __restrict__ blkbase,
    int* __restrict__ row_start){
  __shared__ int sdata[512];
  int tid=threadIdx.x;
  int v=(tid<NBK)?btot[tid]:0;
  sdata[tid]=v; __syncthreads();
  for(int off=1;off<512;off<<=1){
    int y=(tid>=off)?sdata[tid-off]:0;
    __syncthreads();
    sdata[tid]+=y;
    __syncthreads();
  }
  int excl=sdata[tid]-v;
  if(tid<NBK) boff[tid]=excl;
  if(tid==NBK-1){ boff[NBK]=excl+v; row_start[NN]=NE; }
  if(tid<NBK){
    int run=excl;
    for(int b=0;b<NBLKA;b++){
      int c=blkcnt[b*NBK+tid];
      blkbase[b*NBK+tid]=run;
      run+=c;
    }
  }
}

// pack: src (17 bits) | local-dst (7 bits) << 17
__global__ __launch_bounds__(1024) void k_bscatter(const int* __restrict__ src,
    const int* __restrict__ dst, const int* __restrict__ blkbase, uint32* __restrict__ pairs){
  __shared__ int cur[NBK];
  int tid=threadIdx.x;
  for(int i=tid;i<NBK;i+=1024) cur[i]=blkbase[blockIdx.x*NBK+i];
  __syncthreads();
  int e0=blockIdx.x*8192;
  #pragma unroll
  for(int t=0;t<8;t++){
    int e=e0+t*1024+tid;
    if(e<NE){
      int d=dst[e];
      int p=atomicAdd(&cur[d>>7],1);
      pairs[p]=(unsigned)src[e] | ((unsigned)(d&127)<<17);
    }
  }
}

__global__ __launch_bounds__(256) void k_bfinal(const uint32* __restrict__ pairs,
    const int* __restrict__ boff, int* __restrict__ row_start,
    float* __restrict__ inv_sq, int* __restrict__ csr_src){
  __shared__ int degl[128];
  __shared__ int cur[128];
  __shared__ int ssum[2];
  int b=blockIdx.x, tid=threadIdx.x;
  int lo=boff[b], hi=boff[b+1];
  if(tid<128) degl[tid]=0;
  __syncthreads();
  for(int e=lo+tid;e<hi;e+=256) atomicAdd(&degl[pairs[e]>>17],1);
  __syncthreads();
  int v=0,x=0;
  if(tid<128){
    v=degl[tid]; x=v;
    #pragma unroll
    for(int off=1;off<64;off<<=1){
      int y=__shfl_up(x,off,64);
      if((tid&63)>=off) x+=y;
    }
    if((tid&63)==63) ssum[tid>>6]=x;
  }
  __syncthreads();
  if(tid<128){
    int incl=x+((tid>=64)?ssum[0]:0);
    int node=b*128+tid;
    int excl=lo+incl-v;
    if(node<NN){
      row_start[node]=excl;
      cur[tid]=excl;
      inv_sq[node]=1.f/sqrtf((float)(v+1));
    }
  }
  __syncthreads();
  for(int e=lo+tid;e<hi;e+=256){
    uint32 u=pairs[e];
    int p=atomicAdd(&cur[u>>17],1);
    csr_src[p]=(int)(u&0x1FFFFu);
  }
}

// ---------------- 128x128 transpose (Wbil^T) ----------------
__global__ void k_transpose(const float* __restrict__ W, float* __restrict__ Wt){
  int idx=blockIdx.x*256+threadIdx.x;
  if(idx<DD*DD){
    int k=idx>>7, c=idx&127;
    Wt[idx]=W[c*DD+k];
  }
}

// ============ fp32 GEMM: 128x128 tile, 8x8 per thread ============
template<int IN_SIG,int ACT,int OUT_BF16,int FUSE_SCORE>
__global__ __launch_bounds__(256) void k_gemm128(const float* __restrict__ A,
    const float* __restrict__ W, const float* __restrict__ bias,
    float* __restrict__ outf, ushort16* __restrict__ outb,
    const float* __restrict__ aparam, const float* __restrict__ hp,
    const float* __restrict__ bbil, float* __restrict__ score){
  __shared__ float Al[128][132];
  int tid=threadIdx.x;
  int row0=blockIdx.x*128;
  {
    const float4* A4=(const float4*)(A+(size_t)row0*DD);
    #pragma unroll
    for(int i=0;i<16;i++){
      int idx=i*256+tid;
      int r=idx>>5, c=(idx&31)*4;
      float4 v=make_float4(0.f,0.f,0.f,0.f);
      if(row0+r<NN) v=A4[idx];
      if(IN_SIG){ v.x=sigmoidf(v.x); v.y=sigmoidf(v.y); v.z=sigmoidf(v.z); v.w=sigmoidf(v.w); }
      *(float4*)&Al[r][c]=v;
    }
  }
  __syncthreads();
  int tx=tid&15, ty=tid>>4;
  float acc[8][8];
  #pragma unroll
  for(int i=0;i<8;i++)
    #pragma unroll
    for(int c=0;c<8;c++) acc[i][c]=0.f;

  for(int k=0;k<DD;k+=4){
    float wv[4][8];
    #pragma unroll
    for(int r=0;r<4;r++){
      float4 lo=*(const float4*)&W[(size_t)(k+r)*DD+tx*8];
      float4 hi=*(const float4*)&W[(size_t)(k+r)*DD+tx*8+4];
      wv[r][0]=lo.x; wv[r][1]=lo.y; wv[r][2]=lo.z; wv[r][3]=lo.w;
      wv[r][4]=hi.x; wv[r][5]=hi.y; wv[r][6]=hi.z; wv[r][7]=hi.w;
    }
    #pragma unroll
    for(int i=0;i<8;i++){
      float4 a=*(const float4*)&Al[ty+16*i][k];
      #pragma unroll
      for(int c=0;c<8;c++)
        acc[i][c]+=a.x*wv[0][c]+a.y*wv[1][c]+a.z*wv[2][c]+a.w*wv[3][c];
    }
  }

  if(FUSE_SCORE){
    float bb=bbil[0];
    #pragma unroll
    for(int i=0;i<8;i++){
      int r=row0+ty+16*i;
      float p=0.f;
      if(r<NN){
        float4 h0=*(const float4*)&hp[(size_t)r*DD+tx*8];
        float4 h1=*(const float4*)&hp[(size_t)r*DD+tx*8+4];
        p=acc[i][0]*h0.x+acc[i][1]*h0.y+acc[i][2]*h0.z+acc[i][3]*h0.w
         +acc[i][4]*h1.x+acc[i][5]*h1.y+acc[i][6]*h1.z+acc[i][7]*h1.w;
      }
      p+=__shfl_xor(p,1,64); p+=__shfl_xor(p,2,64);
      p+=__shfl_xor(p,4,64); p+=__shfl_xor(p,8,64);
      if(tx==0 && r<NN) score[r]=sigmoidf(p+bb);
    }
    return;
  }
  float bl[8]={0,0,0,0,0,0,0,0};
  if(bias){
    float4 b0=*(const float4*)&bias[tx*8];
    float4 b1=*(const float4*)&bias[tx*8+4];
    bl[0]=b0.x; bl[1]=b0.y; bl[2]=b0.z; bl[3]=b0.w;
    bl[4]=b1.x; bl[5]=b1.y; bl[6]=b1.z; bl[7]=b1.w;
  }
  float ap=ACT?aparam[0]:0.f;
  #pragma unroll
  for(int i=0;i<8;i++){
    int r=row0+ty+16*i;
    if(r<NN){
      float o[8];
      #pragma unroll
      for(int c=0;c<8;c++){
        float t=acc[i][c]+bl[c];
        if(ACT) t=t>=0.f?t:ap*t;
        o[c]=t;
      }
      if(OUT_BF16){
        uint4 pk;
        pk.x=((uint32)f2b(o[1])<<16)|f2b(o[0]);
        pk.y=((uint32)f2b(o[3])<<16)|f2b(o[2]);
        pk.z=((uint32)f2b(o[5])<<16)|f2b(o[4]);
        pk.w=((uint32)f2b(o[7])<<16)|f2b(o[6]);
        *(uint4*)&outb[(size_t)r*DD+tx*8]=pk;
      } else {
        float4 q0; q0.x=o[0]; q0.y=o[1]; q0.z=o[2]; q0.w=o[3];
        float4 q1; q1.x=o[4]; q1.y=o[5]; q1.z=o[6]; q1.w=o[7];
        *(float4*)&outf[(size_t)r*DD+tx*8]=q0;
        *(float4*)&outf[(size_t)r*DD+tx*8+4]=q1;
      }
    }
  }
}

// ---------------- fp32 GCN aggregation: 8-edge unroll, 2 edges/dwordx4 ----
__global__ __launch_bounds__(256) void k_agg_f32(const float* __restrict__ xw,
    const int* __restrict__ row_start, const int* __restrict__ csr,
    const float* __restrict__ inv, const float* __restrict__ bias,
    float* __restrict__ outp){
  int node=blockIdx.x*4+(threadIdx.x>>6);
  if(node>=NN) return;
  int lane=threadIdx.x&63;
  int g=lane>>5, li=lane&31;
  int rs=row_start[node], re=row_start[node+1];
  float a0=0.f,a1=0.f,a2=0.f,a3=0.f;
  int j=rs;
  for(; j+7<re; j+=8){
    int s0=csr[j+g], s1=csr[j+2+g], s2=csr[j+4+g], s3=csr[j+6+g];
    float w0=inv[s0], w1=inv[s1], w2=inv[s2], w3=inv[s3];
    float4 v0=*(const float4*)&xw[(size_t)s0*DD+li*4];
    float4 v1=*(const float4*)&xw[(size_t)s1*DD+li*4];
    float4 v2=*(const float4*)&xw[(size_t)s2*DD+li*4];
    float4 v3=*(const float4*)&xw[(size_t)s3*DD+li*4];
    a0+=v0.x*w0+v1.x*w1+v2.x*w2+v3.x*w3;
    a1+=v0.y*w0+v1.y*w1+v2.y*w2+v3.y*w3;
    a2+=v0.z*w0+v1.z*w1+v2.z*w2+v3.z*w3;
    a3+=v0.w*w0+v1.w*w1+v2.w*w2+v3.w*w3;
  }
  for(; j+1<re; j+=2){
    int s=csr[j+g];
    float w=inv[s];
    float4 v=*(const float4*)&xw[(size_t)s*DD+li*4];
    a0+=v.x*w; a1+=v.y*w; a2+=v.z*w; a3+=v.w*w;
  }
  if(j<re && g==0){
    int s=csr[j]; float w=inv[s];
    float4 v=*(const float4*)&xw[(size_t)s*DD+li*4];
    a0+=v.x*w; a1+=v.y*w; a2+=v.z*w; a3+=v.w*w;
  }
  if(g==0){
    float wd=inv[node];
    float4 v=*(const float4*)&xw[(size_t)node*DD+li*4];
    a0+=v.x*wd; a1+=v.y*wd; a2+=v.z*wd; a3+=v.w*wd;
  }
  a0+=__shfl_xor(a0,32,64); a1+=__shfl_xor(a1,32,64);
  a2+=__shfl_xor(a2,32,64); a3+=__shfl_xor(a3,32,64);
  if(g==0){
    float wn=inv[node];
    float4 bv=*(const float4*)&bias[li*4];
    float4 o;
    o.x=a0*wn+bv.x; o.y=a1*wn+bv.y; o.z=a2*wn+bv.z; o.w=a3*wn+bv.w;
    *(float4*)&outp[(size_t)node*DD+li*4]=o;
  }
}

// ---------------- bf16 GCN aggregation: 4 edges per dwordx4 --------------
// MODE 1: out = sel[node] ? (agg+bias)*score : 0
// MODE 2: out = agg(skip !sel[s]) + bias + addbuf
template<int MODE>
__global__ __launch_bounds__(256) void k_agg_b16(const uint32* __restrict__ xwb,
    const int* __restrict__ row_start, const int* __restrict__ csr,
    const float* __restrict__ inv, const float* __restrict__ bias,
    float* __restrict__ outp, const float* __restrict__ score,
    const unsigned char* __restrict__ sel, const float* __restrict__ addbuf){
  int node=blockIdx.x*4+(threadIdx.x>>6);
  if(node>=NN) return;
  int lane=threadIdx.x&63;
  if(MODE==1 && !sel[node]){
    float2 z; z.x=0.f; z.y=0.f;
    *(float2*)&outp[(size_t)node*DD+lane*2]=z;
    return;
  }
  int g=lane>>4, li=lane&15;
  int rs=row_start[node], re=row_start[node+1];
  float a[8];
  #pragma unroll
  for(int c=0;c<8;c++) a[c]=0.f;
  int j=rs;
  for(; j+7<re; j+=8){
    int sA=csr[j+g], sB=csr[j+4+g];
    if(MODE!=2 || sel[sA]){
      float w=inv[sA];
      uint4 u=*(const uint4*)(xwb+(size_t)sA*64+li*4);
      addbf2(a[0],a[1],u.x,w); addbf2(a[2],a[3],u.y,w);
      addbf2(a[4],a[5],u.z,w); addbf2(a[6],a[7],u.w,w);
    }
    if(MODE!=2 || sel[sB]){
      float w=inv[sB];
      uint4 u=*(const uint4*)(xwb+(size_t)sB*64+li*4);
      addbf2(a[0],a[1],u.x,w); addbf2(a[2],a[3],u.y,w);
      addbf2(a[4],a[5],u.z,w); addbf2(a[6],a[7],u.w,w);
    }
  }
  for(; j+3<re; j+=4){
    int s=csr[j+g];
    if(MODE!=2 || sel[s]){
      float w=inv[s];
      uint4 u=*(const uint4*)(xwb+(size_t)s*64+li*4);
      addbf2(a[0],a[1],u.x,w); addbf2(a[2],a[3],u.y,w);
      addbf2(a[4],a[5],u.z,w); addbf2(a[6],a[7],u.w,w);
    }
  }
  int rem=re-j;
  if(g<rem){
    int s=csr[j+g];
    if(MODE!=2 || sel[s]){
      float w=inv[s];
      uint4 u=*(const uint4*)(xwb+(size_t)s*64+li*4);
      addbf2(a[0],a[1],u.x,w); addbf2(a[2],a[3],u.y,w);
      addbf2(a[4],a[5],u.z,w); addbf2(a[6],a[7],u.w,w);
    }
  }
  if(g==0 && (MODE!=2 || sel[node])){
    float wd=inv[node];
    uint4 u=*(const uint4*)(xwb+(size_t)node*64+li*4);
    addbf2(a[0],a[1],u.x,wd); addbf2(a[2],a[3],u.y,wd);
    addbf2(a[4],a[5],u.z,wd); addbf2(a[6],a[7],u.w,wd);
  }
  #pragma unroll
  for(int c=0;c<8;c++){
    a[c]+=__shfl_xor(a[c],16,64);
    a[c]+=__shfl_xor(a[c],32,64);
  }
  if(g<2){
    float wn=inv[node];
    int cb=li*8+g*4;
    float4 bv=*(const float4*)&bias[cb];
    float r0=a[g*4+0]*wn+bv.x, r1=a[g*4+1]*wn+bv.y;
    float r2=a[g*4+2]*wn+bv.z, r3=a[g*4+3]*wn+bv.w;
    if(MODE==1){
      float sc=score[node];
      r0*=sc; r1*=sc; r2*=sc; r3*=sc;
    } else {
      float4 ad=*(const float4*)&addbuf[(size_t)node*DD+cb];
      r0+=ad.x; r1+=ad.y; r2+=ad.z; r3+=ad.w;
    }
    float4 o; o.x=r0; o.y=r1; o.z=r2; o.w=r3;
    *(float4*)&outp[(size_t)node*DD+cb]=o;
  }
}

// ============ fused single-block top-k select (3-pass radix + ties) ============
__global__ __launch_bounds__(1024) void k_select(const float* __restrict__ score,
    unsigned char* __restrict__ sel){
  __shared__ int h[4096];
  __shared__ int gs[1024];
  __shared__ int tie[2048];
  __shared__ int st[8];   // 0:B0 1:c0 2:P01 3:c1 4:thr 5:needed 6:tiecnt
  int tid=threadIdx.x;
  if(tid==0) st[6]=0;
  // ---- pass 0: bits[31:20]
  for(int i=tid;i<4096;i+=1024) h[i]=0;
  __syncthreads();
  for(int i=tid;i<NN;i+=1024){
    unsigned b=__float_as_uint(score[i]);
    atomicAdd(&h[b>>20],1);
  }
  __syncthreads();
  {
    int s=h[tid*4]+h[tid*4+1]+h[tid*4+2]+h[tid*4+3];
    int x=s; gs[tid]=x; __syncthreads();
    for(int off=1;off<1024;off<<=1){
      int y=(tid+off<1024)?gs[tid+off]:0;
      __syncthreads(); x+=y; gs[tid]=x; __syncthreads();
    }
    int incl=x, above=x-s;
    if(above<KSEL && incl>=KSEL){
      int c=above, B=0;
      for(int b=3;b>=0;b--){ int hb=h[tid*4+b]; if(c+hb>=KSEL){B=tid*4+b;break;} c+=hb; }
      st[0]=B; st[1]=c;
    }
  }
  __syncthreads();
  int B0=st[0];
  // ---- pass 1: bits[19:8] within B0
  for(int i=tid;i<4096;i+=1024) h[i]=0;
  __syncthreads();
  for(int i=tid;i<NN;i+=1024){
    unsigned b=__float_as_uint(score[i]);
    if((int)(b>>20)==B0) atomicAdd(&h[(b>>8)&0xFFF],1);
  }
  __syncthreads();
  {
    int base=st[1];
    int s=h[tid*4]+h[tid*4+1]+h[tid*4+2]+h[tid*4+3];
    int x=s; gs[tid]=x; __syncthreads();
    for(int off=1;off<1024;off<<=1){
      int y=(tid+off<1024)?gs[tid+off]:0;
      __syncthreads(); x+=y; gs[tid]=x; __syncthreads();
    }
    int incl=base+x, above=base+x-s;
    if(above<KSEL && incl>=KSEL){
      int c=above, B=0;
      for(int b=3;b>=0;b--){ int hb=h[tid*4+b]; if(c+hb>=KSEL){B=tid*4+b;break;} c+=hb; }
      st[2]=(B0<<12)|B; st[3]=c;
    }
  }
  __syncthreads();
  int P01=st[2];
  // ---- pass 2: bits[7:0] within P01
  for(int i=tid;i<256;i+=1024) h[i]=0;
  __syncthreads();
  for(int i=tid;i<NN;i+=1024){
    unsigned b=__float_as_uint(score[i]);
    if((int)(b>>8)==P01) atomicAdd(&h[b&0xFF],1);
  }
  __syncthreads();
  {
    int base=st[3];
    int s=0,x=0;
    if(tid<64){ s=h[tid*4]+h[tid*4+1]+h[tid*4+2]+h[tid*4+3]; x=s; }
    gs[tid]=x; __syncthreads();
    for(int off=1;off<64;off<<=1){
      int y=(tid+off<64)?gs[tid+off]:0;
      __syncthreads();
      if(tid<64){ x+=y; gs[tid]=x; }
      __syncthreads();
    }
    if(tid<64){
      int incl=base+x, above=base+x-s;
      if(above<KSEL && incl>=KSEL){
        int c=above, B=0;
        for(int b=3;b>=0;b--){ int hb=h[tid*4+b]; if(c+hb>=KSEL){B=tid*4+b;break;} c+=hb; }
        st[4]=(int)((((unsigned)P01)<<8)|(unsigned)B); st[5]=KSEL-c;
      }
    }
  }
  __syncthreads();
  unsigned thr=(unsigned)st[4];
  // ---- pass 3: mark + collect ties
  for(int i=tid;i<NN;i+=1024){
    unsigned b=__float_as_uint(score[i]);
    unsigned char sv=0;
    if(b>thr) sv=1;
    else if(b==thr){
      int p=atomicAdd(&st[6],1);
      if(p<2048) tie[p]=i;
    }
    sel[i]=sv;
  }
  __syncthreads();
  int m=st[6]; if(m>2048) m=2048;
  int needed=st[5];
  for(int t=tid;t<m;t+=1024){
    int idx=tie[t];
    int rank=0;
    for(int j2=0;j2<m;j2++) rank+=(tie[j2]<idx)?1:0;
    if(rank<needed) sel[idx]=1;
  }
}

// ============================================================================
extern "C" void kernel_launch(void* const* d_in, const int* in_sizes, int n_in,
                              void* d_out, int out_size, void* d_ws, size_t ws_size,
                              hipStream_t stream){
  const float* feat   =(const float*)d_in[0];
  const int*   ei     =(const int*)  d_in[2];
  const int*   src    = ei;
  const int*   dst    = ei + NE;
  const float* Wd     =(const float*)d_in[3];
  const float* bd     =(const float*)d_in[4];
  const float* prelu_a=(const float*)d_in[5];
  const float* Wbil   =(const float*)d_in[6];
  const float* bbil   =(const float*)d_in[7];
  const float* Wg1    =(const float*)d_in[8];
  const float* bg1    =(const float*)d_in[9];
  const float* Wg2    =(const float*)d_in[10];
  const float* bg2    =(const float*)d_in[11];
  const float* Wg3    =(const float*)d_in[12];
  const float* bg3    =(const float*)d_in[13];
  float* out=(float*)d_out;

  char* p=(char*)d_ws;
  auto alloc=[&](size_t bytes)->void*{ void* r=(void*)p; p+=((bytes+255)/256)*256; return r; };
  float* h_pos   =(float*)alloc((size_t)NN*DD*4);
  float* embed   =(float*)alloc((size_t)NN*DD*4);
  float* xw      =(float*)alloc((size_t)NN*DD*4);   // fp32 xw1 / bf16 xw2,xw3 / pairs (early)
  float* score   =(float*)alloc((size_t)NN*4);
  float* inv_sq  =(float*)alloc((size_t)NN*4);
  float* WbT     =(float*)alloc((size_t)DD*DD*4);
  int*   row_st  =(int*)  alloc((size_t)(NN+1)*4);
  int*   csr_src =(int*)  alloc((size_t)NE*4);
  unsigned char* sel=(unsigned char*)alloc(NN);
  int*   btot    =(int*)  alloc((size_t)NBK*4);
  int*   boff    =(int*)  alloc((size_t)(NBK+1)*4);
  int*   blkcnt  =(int*)  alloc((size_t)NBLKA*NBK*4);
  int*   blkbase =(int*)  alloc((size_t)NBLKA*NBK*4);
  uint32* pairs  =(uint32*)xw;                      // aliased: lifetime before xw1
  ushort16* xwb  =(ushort16*)xw;
  float* fine = out;

  const int GB=(NN+127)/128;     // 391 gemm blocks
  const int AB=(NN+3)/4;         // 12500 agg blocks

  hipMemsetAsync(btot, 0, (size_t)NBK*4, stream);

  // graph structure: bucketed counting sort -> CSR + degrees + inv_sqrt
  k_bcount  <<<NBLKA,1024,0,stream>>>(dst, btot, blkcnt);
  k_bscan   <<<1,512,0,stream>>>(btot, boff, blkcnt, blkbase, row_st);
  k_bscatter<<<NBLKA,1024,0,stream>>>(src, dst, blkbase, pairs);
  k_bfinal  <<<NBK,256,0,stream>>>(pairs, boff, row_st, inv_sq, csr_src);
  k_transpose<<<64,256,0,stream>>>(Wbil, WbT);

  // h_pos = prelu(feat @ Wd + bd)
  k_gemm128<0,1,0,0><<<GB,256,0,stream>>>(feat, Wd, bd, h_pos, nullptr, prelu_a, nullptr, nullptr, nullptr);
  // embed = gcn1(h_pos)
  k_gemm128<0,0,0,0><<<GB,256,0,stream>>>(h_pos, Wg1, nullptr, xw, nullptr, nullptr, nullptr, nullptr, nullptr);
  k_agg_f32<<<AB,256,0,stream>>>(xw, row_st, csr_src, inv_sq, bg1, embed);
  // score = sigmoid(rowdot(h_pos, sigmoid(embed)@Wbil^T) + bbil)   [fused]
  k_gemm128<1,0,0,1><<<GB,256,0,stream>>>(embed, WbT, nullptr, nullptr, nullptr, nullptr, h_pos, bbil, score);
  // top-k: fused single-block radix select (+ stable ties)
  k_select<<<1,1024,0,stream>>>(score, sel);
  // fine = sel ? gcn2(embed)*score : 0   (bf16 xw2)
  k_gemm128<0,0,1,0><<<GB,256,0,stream>>>(embed, Wg2, nullptr, nullptr, xwb, nullptr, nullptr, nullptr, nullptr);
  k_agg_b16<1><<<AB,256,0,stream>>>((const uint32*)xwb, row_st, csr_src, inv_sq, bg2, fine, score, sel, nullptr);
  // out = gcn3(fine) + embed             (bf16 xw3, skip exact-zero rows)
  k_gemm128<0,0,1,0><<<GB,256,0,stream>>>(fine, Wg3, nullptr, nullptr, xwb, nullptr, nullptr, nullptr, nullptr);
  k_agg_b16<2><<<AB,256,0,stream>>>((const uint32*)xwb, row_st, csr_src, inv_sq, bg3, out, nullptr, sel, embed);
}

// Round 7
// 371.659 us; speedup vs baseline: 1.7069x; 1.0615x over previous
//
#include <hip/hip_runtime.h>
#include <hip/hip_bf16.h>

#define NN 50000
#define NE 800000
#define DD 128
#define KSEL 25000
#define NBK 391                 // buckets of 128 nodes (graph build)
#define NBLKA 98                // (NE+8191)/8192

typedef unsigned int uint32;
typedef unsigned short ushort16;

__device__ __forceinline__ float sigmoidf(float x){ return 1.f/(1.f+__expf(-x)); }

__device__ __forceinline__ unsigned short f2b(float f){
  union{float f; unsigned u;} v; v.f=f;
  unsigned r=(v.u + 0x7fffu + ((v.u>>16)&1u))>>16;
  return (unsigned short)r;
}

__device__ __forceinline__ void addbf2(float&lo,float&hi,uint32 u,float w){
  lo+=__uint_as_float(u<<16)*w;
  hi+=__uint_as_float(u&0xffff0000u)*w;
}

// ================= graph build: bucketed counting sort =================
__global__ __launch_bounds__(1024) void k_bcount(const int* __restrict__ dst,
    int* __restrict__ btot, int* __restrict__ blkcnt){
  __shared__ int h[NBK];
  int tid=threadIdx.x;
  for(int i=tid;i<NBK;i+=1024) h[i]=0;
  __syncthreads();
  int e0=blockIdx.x*8192;
  #pragma unroll
  for(int t=0;t<8;t++){
    int e=e0+t*1024+tid;
    if(e<NE) atomicAdd(&h[dst[e]>>7],1);
  }
  __syncthreads();
  for(int i=tid;i<NBK;i+=1024){
    int c=h[i];
    blkcnt[blockIdx.x*NBK+i]=c;
    if(c) atomicAdd(&btot[i],c);
  }
}

__global__ __launch_bounds__(512) void k_bscan(const int* __restrict__ btot,
    int* __restrict__ boff, const int* __restrict__ blkcnt, int* __restrict__ blkbase,
    int* __restrict__ row_start){
  __shared__ int sdata[512];
  int tid=threadIdx.x;
  int v=(tid<NBK)?btot[tid]:0;
  sdata[tid]=v; __syncthreads();
  for(int off=1;off<512;off<<=1){
    int y=(tid>=off)?sdata[tid-off]:0;
    __syncthreads();
    sdata[tid]+=y;
    __syncthreads();
  }
  int excl=sdata[tid]-v;
  if(tid<NBK) boff[tid]=excl;
  if(tid==NBK-1){ boff[NBK]=excl+v; row_start[NN]=NE; }
  if(tid<NBK){
    int run=excl;
    for(int b=0;b<NBLKA;b++){
      int c=blkcnt[b*NBK+tid];
      blkbase[b*NBK+tid]=run;
      run+=c;
    }
  }
}

// pack: src (17 bits) | local-dst (7 bits) << 17
__global__ __launch_bounds__(1024) void k_bscatter(const int* __restrict__ src,
    const int* __restrict__ dst, const int* __restrict__ blkbase, uint32* __restrict__ pairs){
  __shared__ int cur[NBK];
  int tid=threadIdx.x;
  for(int i=tid;i<NBK;i+=1024) cur[i]=blkbase[blockIdx.x*NBK+i];
  __syncthreads();
  int e0=blockIdx.x*8192;
  #pragma unroll
  for(int t=0;t<8;t++){
    int e=e0+t*1024+tid;
    if(e<NE){
      int d=dst[e];
      int p=atomicAdd(&cur[d>>7],1);
      pairs[p]=(unsigned)src[e] | ((unsigned)(d&127)<<17);
    }
  }
}

__global__ __launch_bounds__(256) void k_bfinal(const uint32* __restrict__ pairs,
    const int* __restrict__ boff, int* __restrict__ row_start,
    float* __restrict__ inv_sq, int* __restrict__ csr_src){
  __shared__ int degl[128];
  __shared__ int cur[128];
  __shared__ int ssum[2];
  int b=blockIdx.x, tid=threadIdx.x;
  int lo=boff[b], hi=boff[b+1];
  if(tid<128) degl[tid]=0;
  __syncthreads();
  for(int e=lo+tid;e<hi;e+=256) atomicAdd(&degl[pairs[e]>>17],1);
  __syncthreads();
  int v=0,x=0;
  if(tid<128){
    v=degl[tid]; x=v;
    #pragma unroll
    for(int off=1;off<64;off<<=1){
      int y=__shfl_up(x,off,64);
      if((tid&63)>=off) x+=y;
    }
    if((tid&63)==63) ssum[tid>>6]=x;
  }
  __syncthreads();
  if(tid<128){
    int incl=x+((tid>=64)?ssum[0]:0);
    int node=b*128+tid;
    int excl=lo+incl-v;
    if(node<NN){
      row_start[node]=excl;
      cur[tid]=excl;
      inv_sq[node]=1.f/sqrtf((float)(v+1));
    }
  }
  __syncthreads();
  for(int e=lo+tid;e<hi;e+=256){
    uint32 u=pairs[e];
    int p=atomicAdd(&cur[u>>17],1);
    csr_src[p]=(int)(u&0x1FFFFu);
  }
}

// ---------------- 128x128 transpose (Wbil^T) ----------------
__global__ void k_transpose(const float* __restrict__ W, float* __restrict__ Wt){
  int idx=blockIdx.x*256+threadIdx.x;
  if(idx<DD*DD){
    int k=idx>>7, c=idx&127;
    Wt[idx]=W[c*DD+k];
  }
}

// ============ fp32 GEMM: 96x128 tile, 6x8 per thread (3 blocks/CU) ============
template<int IN_SIG,int ACT,int OUT_BF16,int FUSE_SCORE>
__global__ __launch_bounds__(256) void k_gemm96(const float* __restrict__ A,
    const float* __restrict__ W, const float* __restrict__ bias,
    float* __restrict__ outf, ushort16* __restrict__ outb,
    const float* __restrict__ aparam, const float* __restrict__ hp,
    const float* __restrict__ bbil, float* __restrict__ score){
  __shared__ float Al[96][132];           // 50.7 KB -> 3 blocks/CU
  int tid=threadIdx.x;
  int row0=blockIdx.x*96;
  {
    const float4* A4=(const float4*)(A+(size_t)row0*DD);
    #pragma unroll
    for(int i=0;i<12;i++){
      int idx=i*256+tid;                  // 0..3071
      int r=idx>>5, c=(idx&31)*4;
      float4 v=make_float4(0.f,0.f,0.f,0.f);
      if(row0+r<NN) v=A4[idx];
      if(IN_SIG){ v.x=sigmoidf(v.x); v.y=sigmoidf(v.y); v.z=sigmoidf(v.z); v.w=sigmoidf(v.w); }
      *(float4*)&Al[r][c]=v;
    }
  }
  __syncthreads();
  int tx=tid&15, ty=tid>>4;               // cols tx*8..+7 ; rows ty+16*i (i<6)
  float acc[6][8];
  #pragma unroll
  for(int i=0;i<6;i++)
    #pragma unroll
    for(int c=0;c<8;c++) acc[i][c]=0.f;

  for(int k=0;k<DD;k+=4){
    float wv[4][8];
    #pragma unroll
    for(int r=0;r<4;r++){
      float4 lo=*(const float4*)&W[(size_t)(k+r)*DD+tx*8];
      float4 hi=*(const float4*)&W[(size_t)(k+r)*DD+tx*8+4];
      wv[r][0]=lo.x; wv[r][1]=lo.y; wv[r][2]=lo.z; wv[r][3]=lo.w;
      wv[r][4]=hi.x; wv[r][5]=hi.y; wv[r][6]=hi.z; wv[r][7]=hi.w;
    }
    #pragma unroll
    for(int i=0;i<6;i++){
      float4 a=*(const float4*)&Al[ty+16*i][k];
      #pragma unroll
      for(int c=0;c<8;c++)
        acc[i][c]+=a.x*wv[0][c]+a.y*wv[1][c]+a.z*wv[2][c]+a.w*wv[3][c];
    }
  }

  if(FUSE_SCORE){
    float bb=bbil[0];
    #pragma unroll
    for(int i=0;i<6;i++){
      int r=row0+ty+16*i;
      float p=0.f;
      if(r<NN){
        float4 h0=*(const float4*)&hp[(size_t)r*DD+tx*8];
        float4 h1=*(const float4*)&hp[(size_t)r*DD+tx*8+4];
        p=acc[i][0]*h0.x+acc[i][1]*h0.y+acc[i][2]*h0.z+acc[i][3]*h0.w
         +acc[i][4]*h1.x+acc[i][5]*h1.y+acc[i][6]*h1.z+acc[i][7]*h1.w;
      }
      p+=__shfl_xor(p,1,64); p+=__shfl_xor(p,2,64);
      p+=__shfl_xor(p,4,64); p+=__shfl_xor(p,8,64);
      if(tx==0 && r<NN) score[r]=sigmoidf(p+bb);
    }
    return;
  }
  float bl[8]={0,0,0,0,0,0,0,0};
  if(bias){
    float4 b0=*(const float4*)&bias[tx*8];
    float4 b1=*(const float4*)&bias[tx*8+4];
    bl[0]=b0.x; bl[1]=b0.y; bl[2]=b0.z; bl[3]=b0.w;
    bl[4]=b1.x; bl[5]=b1.y; bl[6]=b1.z; bl[7]=b1.w;
  }
  float ap=ACT?aparam[0]:0.f;
  #pragma unroll
  for(int i=0;i<6;i++){
    int r=row0+ty+16*i;
    if(r<NN){
      float o[8];
      #pragma unroll
      for(int c=0;c<8;c++){
        float t=acc[i][c]+bl[c];
        if(ACT) t=t>=0.f?t:ap*t;
        o[c]=t;
      }
      if(OUT_BF16){
        uint4 pk;
        pk.x=((uint32)f2b(o[1])<<16)|f2b(o[0]);
        pk.y=((uint32)f2b(o[3])<<16)|f2b(o[2]);
        pk.z=((uint32)f2b(o[5])<<16)|f2b(o[4]);
        pk.w=((uint32)f2b(o[7])<<16)|f2b(o[6]);
        *(uint4*)&outb[(size_t)r*DD+tx*8]=pk;
      } else {
        float4 q0; q0.x=o[0]; q0.y=o[1]; q0.z=o[2]; q0.w=o[3];
        float4 q1; q1.x=o[4]; q1.y=o[5]; q1.z=o[6]; q1.w=o[7];
        *(float4*)&outf[(size_t)r*DD+tx*8]=q0;
        *(float4*)&outf[(size_t)r*DD+tx*8+4]=q1;
      }
    }
  }
}

// ---------------- fp32 GCN aggregation: 8-edge unroll, 2 edges/dwordx4 ----
__global__ __launch_bounds__(256) void k_agg_f32(const float* __restrict__ xw,
    const int* __restrict__ row_start, const int* __restrict__ csr,
    const float* __restrict__ inv, const float* __restrict__ bias,
    float* __restrict__ outp){
  int node=blockIdx.x*4+(threadIdx.x>>6);
  if(node>=NN) return;
  int lane=threadIdx.x&63;
  int g=lane>>5, li=lane&31;
  int rs=row_start[node], re=row_start[node+1];
  float a0=0.f,a1=0.f,a2=0.f,a3=0.f;
  int j=rs;
  for(; j+7<re; j+=8){
    int s0=csr[j+g], s1=csr[j+2+g], s2=csr[j+4+g], s3=csr[j+6+g];
    float w0=inv[s0], w1=inv[s1], w2=inv[s2], w3=inv[s3];
    float4 v0=*(const float4*)&xw[(size_t)s0*DD+li*4];
    float4 v1=*(const float4*)&xw[(size_t)s1*DD+li*4];
    float4 v2=*(const float4*)&xw[(size_t)s2*DD+li*4];
    float4 v3=*(const float4*)&xw[(size_t)s3*DD+li*4];
    a0+=v0.x*w0+v1.x*w1+v2.x*w2+v3.x*w3;
    a1+=v0.y*w0+v1.y*w1+v2.y*w2+v3.y*w3;
    a2+=v0.z*w0+v1.z*w1+v2.z*w2+v3.z*w3;
    a3+=v0.w*w0+v1.w*w1+v2.w*w2+v3.w*w3;
  }
  for(; j+1<re; j+=2){
    int s=csr[j+g];
    float w=inv[s];
    float4 v=*(const float4*)&xw[(size_t)s*DD+li*4];
    a0+=v.x*w; a1+=v.y*w; a2+=v.z*w; a3+=v.w*w;
  }
  if(j<re && g==0){
    int s=csr[j]; float w=inv[s];
    float4 v=*(const float4*)&xw[(size_t)s*DD+li*4];
    a0+=v.x*w; a1+=v.y*w; a2+=v.z*w; a3+=v.w*w;
  }
  if(g==0){
    float wd=inv[node];
    float4 v=*(const float4*)&xw[(size_t)node*DD+li*4];
    a0+=v.x*wd; a1+=v.y*wd; a2+=v.z*wd; a3+=v.w*wd;
  }
  a0+=__shfl_xor(a0,32,64); a1+=__shfl_xor(a1,32,64);
  a2+=__shfl_xor(a2,32,64); a3+=__shfl_xor(a3,32,64);
  if(g==0){
    float wn=inv[node];
    float4 bv=*(const float4*)&bias[li*4];
    float4 o;
    o.x=a0*wn+bv.x; o.y=a1*wn+bv.y; o.z=a2*wn+bv.z; o.w=a3*wn+bv.w;
    *(float4*)&outp[(size_t)node*DD+li*4]=o;
  }
}

// ---------------- bf16 GCN aggregation: 4 edges per dwordx4 --------------
// MODE 1: out = sel[node] ? (agg+bias)*score : 0
// MODE 2: out = agg(skip !sel[s]) + bias + addbuf
template<int MODE>
__global__ __launch_bounds__(256) void k_agg_b16(const uint32* __restrict__ xwb,
    const int* __restrict__ row_start, const int* __restrict__ csr,
    const float* __restrict__ inv, const float* __restrict__ bias,
    float* __restrict__ outp, const float* __restrict__ score,
    const unsigned char* __restrict__ sel, const float* __restrict__ addbuf){
  int node=blockIdx.x*4+(threadIdx.x>>6);
  if(node>=NN) return;
  int lane=threadIdx.x&63;
  if(MODE==1 && !sel[node]){
    float2 z; z.x=0.f; z.y=0.f;
    *(float2*)&outp[(size_t)node*DD+lane*2]=z;
    return;
  }
  int g=lane>>4, li=lane&15;
  int rs=row_start[node], re=row_start[node+1];
  float a[8];
  #pragma unroll
  for(int c=0;c<8;c++) a[c]=0.f;
  int j=rs;
  for(; j+7<re; j+=8){
    int sA=csr[j+g], sB=csr[j+4+g];
    if(MODE!=2 || sel[sA]){
      float w=inv[sA];
      uint4 u=*(const uint4*)(xwb+(size_t)sA*64+li*4);
      addbf2(a[0],a[1],u.x,w); addbf2(a[2],a[3],u.y,w);
      addbf2(a[4],a[5],u.z,w); addbf2(a[6],a[7],u.w,w);
    }
    if(MODE!=2 || sel[sB]){
      float w=inv[sB];
      uint4 u=*(const uint4*)(xwb+(size_t)sB*64+li*4);
      addbf2(a[0],a[1],u.x,w); addbf2(a[2],a[3],u.y,w);
      addbf2(a[4],a[5],u.z,w); addbf2(a[6],a[7],u.w,w);
    }
  }
  for(; j+3<re; j+=4){
    int s=csr[j+g];
    if(MODE!=2 || sel[s]){
      float w=inv[s];
      uint4 u=*(const uint4*)(xwb+(size_t)s*64+li*4);
      addbf2(a[0],a[1],u.x,w); addbf2(a[2],a[3],u.y,w);
      addbf2(a[4],a[5],u.z,w); addbf2(a[6],a[7],u.w,w);
    }
  }
  int rem=re-j;
  if(g<rem){
    int s=csr[j+g];
    if(MODE!=2 || sel[s]){
      float w=inv[s];
      uint4 u=*(const uint4*)(xwb+(size_t)s*64+li*4);
      addbf2(a[0],a[1],u.x,w); addbf2(a[2],a[3],u.y,w);
      addbf2(a[4],a[5],u.z,w); addbf2(a[6],a[7],u.w,w);
    }
  }
  if(g==0 && (MODE!=2 || sel[node])){
    float wd=inv[node];
    uint4 u=*(const uint4*)(xwb+(size_t)node*64+li*4);
    addbf2(a[0],a[1],u.x,wd); addbf2(a[2],a[3],u.y,wd);
    addbf2(a[4],a[5],u.z,wd); addbf2(a[6],a[7],u.w,wd);
  }
  #pragma unroll
  for(int c=0;c<8;c++){
    a[c]+=__shfl_xor(a[c],16,64);
    a[c]+=__shfl_xor(a[c],32,64);
  }
  if(g<2){
    float wn=inv[node];
    int cb=li*8+g*4;
    float4 bv=*(const float4*)&bias[cb];
    float r0=a[g*4+0]*wn+bv.x, r1=a[g*4+1]*wn+bv.y;
    float r2=a[g*4+2]*wn+bv.z, r3=a[g*4+3]*wn+bv.w;
    if(MODE==1){
      float sc=score[node];
      r0*=sc; r1*=sc; r2*=sc; r3*=sc;
    } else {
      float4 ad=*(const float4*)&addbuf[(size_t)node*DD+cb];
      r0+=ad.x; r1+=ad.y; r2+=ad.z; r3+=ad.w;
    }
    float4 o; o.x=r0; o.y=r1; o.z=r2; o.w=r3;
    *(float4*)&outp[(size_t)node*DD+cb]=o;
  }
}

// ---------------- 3-pass radix select, LDS-privatized (multi-block) ----------
template<int NB,int PASS>
__global__ __launch_bounds__(256) void k_hist(const float* __restrict__ score,
    int* __restrict__ ghist, const int* __restrict__ ctrl){
  __shared__ int lh[NB];
  int tid=threadIdx.x;
  for(int i=tid;i<NB;i+=256) lh[i]=0;
  __syncthreads();
  int p0=0,p01=0;
  if(PASS==1) p0=ctrl[0];
  if(PASS==2) p01=ctrl[2];
  for(int i=blockIdx.x*256+tid; i<NN; i+=gridDim.x*256){
    unsigned b=__float_as_uint(score[i]);
    if(PASS==0) atomicAdd(&lh[b>>20],1);
    else if(PASS==1){ if((int)(b>>20)==p0) atomicAdd(&lh[(b>>8)&0xFFF],1); }
    else { if((int)(b>>8)==p01) atomicAdd(&lh[b&0xFF],1); }
  }
  __syncthreads();
  for(int i=tid;i<NB;i+=256){ int v=lh[i]; if(v) atomicAdd(&ghist[i],v); }
}

template<int NB,int PASS>
__global__ void k_findb(const int* __restrict__ hist, int* __restrict__ ctrl){
  const int NT=NB/4;
  __shared__ int gsum[NT];
  int t=threadIdx.x;
  int s=hist[t*4]+hist[t*4+1]+hist[t*4+2]+hist[t*4+3];
  int x=s; gsum[t]=x; __syncthreads();
  for(int off=1;off<NT;off<<=1){
    int y=(t+off<NT)?gsum[t+off]:0;
    __syncthreads();
    x+=y; gsum[t]=x; __syncthreads();
  }
  int base;
  if(PASS==0) base=0; else if(PASS==1) base=ctrl[1]; else base=ctrl[3];
  int above=base+((t<NT-1)?gsum[t+1]:0);
  int incl=base+gsum[t];
  if(above<KSEL && incl>=KSEL){
    int c=above, B=0;
    for(int b=3;b>=0;b--){
      int hb=hist[t*4+b];
      if(c+hb>=KSEL){ B=t*4+b; break; }
      c+=hb;
    }
    if(PASS==0){ ctrl[0]=B; ctrl[1]=c; }
    else if(PASS==1){ ctrl[2]=(ctrl[0]<<12)|B; ctrl[3]=c; }
    else { ctrl[4]=(int)((((unsigned)ctrl[2])<<8)|(unsigned)B); ctrl[5]=KSEL-c; }
  }
}

__global__ void k_sel(const float* __restrict__ score, int* __restrict__ ctrl,
                      int* __restrict__ tie_list, unsigned char* __restrict__ sel){
  int i=blockIdx.x*256+threadIdx.x;
  if(i>=NN) return;
  unsigned b=__float_as_uint(score[i]);
  unsigned thr=(unsigned)ctrl[4];
  if(b>thr){ sel[i]=1; }
  else if(b==thr){
    sel[i]=0;
    int p=atomicAdd(&ctrl[6],1);
    if(p<4096) tie_list[p]=i;
  } else sel[i]=0;
}

__global__ __launch_bounds__(256) void k_tie(const int* __restrict__ ctrl,
    const int* __restrict__ tie_list, unsigned char* __restrict__ sel){
  int m=ctrl[6]; if(m>4096) m=4096;
  int needed=ctrl[5];
  for(int t=threadIdx.x; t<m; t+=blockDim.x){
    int idx=tie_list[t];
    int rank=0;
    for(int j=0;j<m;j++) rank+=(tie_list[j]<idx)?1:0;
    if(rank<needed) sel[idx]=1;
  }
}

// ============================================================================
extern "C" void kernel_launch(void* const* d_in, const int* in_sizes, int n_in,
                              void* d_out, int out_size, void* d_ws, size_t ws_size,
                              hipStream_t stream){
  const float* feat   =(const float*)d_in[0];
  const int*   ei     =(const int*)  d_in[2];
  const int*   src    = ei;
  const int*   dst    = ei + NE;
  const float* Wd     =(const float*)d_in[3];
  const float* bd     =(const float*)d_in[4];
  const float* prelu_a=(const float*)d_in[5];
  const float* Wbil   =(const float*)d_in[6];
  const float* bbil   =(const float*)d_in[7];
  const float* Wg1    =(const float*)d_in[8];
  const float* bg1    =(const float*)d_in[9];
  const float* Wg2    =(const float*)d_in[10];
  const float* bg2    =(const float*)d_in[11];
  const float* Wg3    =(const float*)d_in[12];
  const float* bg3    =(const float*)d_in[13];
  float* out=(float*)d_out;

  char* p=(char*)d_ws;
  auto alloc=[&](size_t bytes)->void*{ void* r=(void*)p; p+=((bytes+255)/256)*256; return r; };
  float* h_pos   =(float*)alloc((size_t)NN*DD*4);
  float* embed   =(float*)alloc((size_t)NN*DD*4);
  float* xw      =(float*)alloc((size_t)NN*DD*4);   // fp32 xw1 / bf16 xw2,xw3 / pairs (early)
  float* score   =(float*)alloc((size_t)NN*4);
  float* inv_sq  =(float*)alloc((size_t)NN*4);
  float* WbT     =(float*)alloc((size_t)DD*DD*4);
  int*   row_st  =(int*)  alloc((size_t)(NN+1)*4);
  int*   csr_src =(int*)  alloc((size_t)NE*4);
  int*   ctrl    =(int*)  alloc(64);
  int*   hist0   =(int*)  alloc(4096*4);
  int*   hist1   =(int*)  alloc(4096*4);
  int*   hist2   =(int*)  alloc(256*4);
  int*   tie_list=(int*)  alloc(4096*4);
  unsigned char* sel=(unsigned char*)alloc(NN);
  int*   btot    =(int*)  alloc((size_t)NBK*4);
  int*   boff    =(int*)  alloc((size_t)(NBK+1)*4);
  int*   blkcnt  =(int*)  alloc((size_t)NBLKA*NBK*4);
  int*   blkbase =(int*)  alloc((size_t)NBLKA*NBK*4);
  uint32* pairs  =(uint32*)xw;                      // aliased: lifetime before xw1
  ushort16* xwb  =(ushort16*)xw;
  float* fine = out;

  const int NB=(NN+255)/256;
  const int GB=(NN+95)/96;       // 521 gemm blocks
  const int AB=(NN+3)/4;         // 12500 agg blocks

  hipMemsetAsync(ctrl, 0, (size_t)((char*)tie_list-(char*)ctrl), stream);
  hipMemsetAsync(btot, 0, (size_t)NBK*4, stream);

  // graph structure: bucketed counting sort -> CSR + degrees + inv_sqrt
  k_bcount  <<<NBLKA,1024,0,stream>>>(dst, btot, blkcnt);
  k_bscan   <<<1,512,0,stream>>>(btot, boff, blkcnt, blkbase, row_st);
  k_bscatter<<<NBLKA,1024,0,stream>>>(src, dst, blkbase, pairs);
  k_bfinal  <<<NBK,256,0,stream>>>(pairs, boff, row_st, inv_sq, csr_src);
  k_transpose<<<64,256,0,stream>>>(Wbil, WbT);

  // h_pos = prelu(feat @ Wd + bd)
  k_gemm96<0,1,0,0><<<GB,256,0,stream>>>(feat, Wd, bd, h_pos, nullptr, prelu_a, nullptr, nullptr, nullptr);
  // embed = gcn1(h_pos)
  k_gemm96<0,0,0,0><<<GB,256,0,stream>>>(h_pos, Wg1, nullptr, xw, nullptr, nullptr, nullptr, nullptr, nullptr);
  k_agg_f32<<<AB,256,0,stream>>>(xw, row_st, csr_src, inv_sq, bg1, embed);
  // score = sigmoid(rowdot(h_pos, sigmoid(embed)@Wbil^T) + bbil)   [fused]
  k_gemm96<1,0,0,1><<<GB,256,0,stream>>>(embed, WbT, nullptr, nullptr, nullptr, nullptr, h_pos, bbil, score);
  // top-k: 3-pass LDS-privatized radix select (multi-block)
  k_hist<4096,0><<<64,256,0,stream>>>(score, hist0, ctrl);
  k_findb<4096,0><<<1,1024,0,stream>>>(hist0, ctrl);
  k_hist<4096,1><<<64,256,0,stream>>>(score, hist1, ctrl);
  k_findb<4096,1><<<1,1024,0,stream>>>(hist1, ctrl);
  k_hist<256,2><<<64,256,0,stream>>>(score, hist2, ctrl);
  k_findb<256,2><<<1,64,0,stream>>>(hist2, ctrl);
  k_sel<<<NB,256,0,stream>>>(score, ctrl, tie_list, sel);
  k_tie<<<1,256,0,stream>>>(ctrl, tie_list, sel);
  // fine = sel ? gcn2(embed)*score : 0   (bf16 xw2)
  k_gemm96<0,0,1,0><<<GB,256,0,stream>>>(embed, Wg2, nullptr, nullptr, xwb, nullptr, nullptr, nullptr, nullptr);
  k_agg_b16<1><<<AB,256,0,stream>>>((const uint32*)xwb, row_st, csr_src, inv_sq, bg2, fine, score, sel, nullptr);
  // out = gcn3(fine) + embed             (bf16 xw3, skip exact-zero rows)
  k_gemm96<0,0,1,0><<<GB,256,0,stream>>>(fine, Wg3, nullptr, nullptr, xwb, nullptr, nullptr, nullptr, nullptr);
  k_agg_b16<2><<<AB,256,0,stream>>>((const uint32*)xwb, row_st, csr_src, inv_sq, bg3, out, nullptr, sel, embed);
}